// Round 5
// baseline (1709.266 us; speedup 1.0000x reference)
//
#include <hip/hip_runtime.h>
#include <hip/hip_bf16.h>
#include <stdint.h>

// R5: materialized token gather. Expert gate/up GEMMs read a pre-gathered,
// contiguous xg (direct staging, L2-friendly like the shared dual) instead of
// gathering rows inside the GEMM (R4: ~27% MfmaUtil from L2 thrash on the
// vmcnt(0) drains). Gather batch size GB adapts to ws_size; GB=0 == R4 path.

typedef float f32x4 __attribute__((ext_vector_type(4)));
typedef int   i32x4 __attribute__((ext_vector_type(4)));
typedef __hip_bfloat16 bf16;

#define DEV __device__ __forceinline__

DEV void mfma16(f32x4& c, const i32x4& a, const i32x4& b) {
    asm("v_mfma_f32_16x16x32_bf16 %0, %1, %2, %0" : "+v"(c) : "v"(a), "v"(b));
}

// Direct stage: [ROWS][64] bf16 tile (row stride ldK elems) -> LDS linear,
// T2 XOR swizzle applied on the global source (rule #21).
template<int ROWS>
DEV void stage(const bf16* gtile, long ldK, char* lds, int tid) {
    const int wid = tid >> 6, lane = tid & 63;
    const int swz = ((lane & 7) ^ (lane >> 3)) << 4;
    constexpr int NISS = (ROWS * 128) / 4096;
    #pragma unroll
    for (int i = 0; i < NISS; i++) {
        const int o = i * 4096 + wid * 1024;
        const int row = (o >> 7) + (lane >> 3);
        const char* ga = (const char*)gtile + (long)row * (ldK * 2) + swz;
        __builtin_amdgcn_global_load_lds(
            (const __attribute__((address_space(1))) void*)ga,
            (__attribute__((address_space(3))) void*)(lds + o), 16, 0, 0);
    }
}

// Indirect stage: per-lane row byte-offsets precomputed (gathered rows).
template<int ROWS>
DEV void stage_idx(const char* base, const long* roff, int ktb, char* lds,
                   int tid, int swz) {
    const int wid = tid >> 6;
    constexpr int NISS = (ROWS * 128) / 4096;
    #pragma unroll
    for (int i = 0; i < NISS; i++) {
        const int o = i * 4096 + wid * 1024;
        const char* ga = base + roff[i] + ktb + swz;
        __builtin_amdgcn_global_load_lds(
            (const __attribute__((address_space(1))) void*)ga,
            (__attribute__((address_space(3))) void*)(lds + o), 16, 0, 0);
    }
}

DEV i32x4 ldsfrag(const char* lds, int row, int kbyte) {
    const int off = (row << 7) + (kbyte ^ ((row & 7) << 4));
    return *(const i32x4*)(lds + off);
}

// ---------------- transpose + fp32->bf16 convert (z-batched) ----------------
__global__ __launch_bounds__(256) void tcvt(const float* __restrict__ src,
        bf16* __restrict__ dst, int Cd, long dld, long sz, long dz) {
    __shared__ float t[64][65];
    const long z = blockIdx.z;
    src += z * sz; dst += z * dz;
    const int cb = blockIdx.x * 64, rb = blockIdx.y * 64;
    const int tx = threadIdx.x & 63, ty = threadIdx.x >> 6;
    #pragma unroll
    for (int i = 0; i < 16; i++) {
        const int r = ty + i * 4;
        t[r][tx] = src[(long)(rb + r) * Cd + cb + tx];
    }
    __syncthreads();
    #pragma unroll
    for (int i = 0; i < 16; i++) {
        const int c = ty + i * 4;
        dst[(long)(cb + c) * dld + rb + tx] = __float2bfloat16(t[tx][c]);
    }
}

// ---------------- x fp32 -> bf16 ----------------
__global__ __launch_bounds__(256) void cvtx(const float* __restrict__ x,
        bf16* __restrict__ xb, long n4) {
    long i = (long)blockIdx.x * blockDim.x + threadIdx.x;
    const long stride = (long)gridDim.x * blockDim.x;
    for (; i < n4; i += stride) {
        const float4 v = ((const float4*)x)[i];
        union { bf16 h[4]; ushort4 u; } cu;
        cu.h[0] = __float2bfloat16(v.x); cu.h[1] = __float2bfloat16(v.y);
        cu.h[2] = __float2bfloat16(v.z); cu.h[3] = __float2bfloat16(v.w);
        ((ushort4*)xb)[i] = cu.u;
    }
}

// ---------------- router: fp32 logits, softmax, top-4, renorm ----------------
__global__ __launch_bounds__(256) void router(const float* __restrict__ x,
        const float* __restrict__ gw, const float* __restrict__ segw,
        int* __restrict__ tidx, float* __restrict__ tw,
        float* __restrict__ sg, int C) {
    const int lane = threadIdx.x & 63;
    const long t = (long)blockIdx.x * 4 + (threadIdx.x >> 6);
    const float* xr = x + t * C;
    float a[9];
    #pragma unroll
    for (int e = 0; e < 9; e++) a[e] = 0.f;
    for (int c = lane; c < C; c += 64) {
        const float xv = xr[c];
        const float4* g4 = (const float4*)(gw + (long)c * 8);
        const float4 g0 = g4[0], g1 = g4[1];
        a[0] += xv * g0.x; a[1] += xv * g0.y; a[2] += xv * g0.z; a[3] += xv * g0.w;
        a[4] += xv * g1.x; a[5] += xv * g1.y; a[6] += xv * g1.z; a[7] += xv * g1.w;
        a[8] += xv * segw[c];
    }
    #pragma unroll
    for (int e = 0; e < 9; e++) {
        #pragma unroll
        for (int o = 32; o; o >>= 1) a[e] += __shfl_xor(a[e], o, 64);
    }
    if (lane == 0) {
        float m = a[0];
        #pragma unroll
        for (int e = 1; e < 8; e++) m = fmaxf(m, a[e]);
        float p[8]; float s = 0.f;
        #pragma unroll
        for (int e = 0; e < 8; e++) { p[e] = expf(a[e] - m); s += p[e]; }
        #pragma unroll
        for (int e = 0; e < 8; e++) p[e] /= s;
        bool used[8] = {false,false,false,false,false,false,false,false};
        float wsum = 0.f; int idx[4]; float wv[4];
        for (int k = 0; k < 4; k++) {       // strict > : lowest index on ties
            float best = -1.f; int bi = 0;
            for (int e = 0; e < 8; e++)
                if (!used[e] && p[e] > best) { best = p[e]; bi = e; }
            used[bi] = true; idx[k] = bi; wv[k] = best; wsum += best;
        }
        int4 iv; float4 wv4;
        iv.x = idx[0]; iv.y = idx[1]; iv.z = idx[2]; iv.w = idx[3];
        wv4.x = wv[0] / wsum; wv4.y = wv[1] / wsum;
        wv4.z = wv[2] / wsum; wv4.w = wv[3] / wsum;
        ((int4*)tidx)[t] = iv;
        ((float4*)tw)[t] = wv4;
        sg[t] = 1.f / (1.f + expf(-a[8]));
    }
}

// ---------------- per-expert ordered token lists (deterministic) ------------
__global__ __launch_bounds__(256) void build_lists(const int* __restrict__ tidx,
        const float* __restrict__ tw, int* __restrict__ tok,
        float* __restrict__ wl, int* __restrict__ cnt, int N) {
    const int e = blockIdx.x;
    const int tid = threadIdx.x;
    const int per = N / 256;
    __shared__ int csum[256];
    int c = 0;
    for (int i = 0; i < per; i++) {
        const int4 id4 = ((const int4*)tidx)[tid * per + i];
        if (id4.x == e || id4.y == e || id4.z == e || id4.w == e) c++;
    }
    csum[tid] = c;
    __syncthreads();
    for (int o = 1; o < 256; o <<= 1) {
        const int v = (tid >= o) ? csum[tid - o] : 0;
        __syncthreads();
        csum[tid] += v;
        __syncthreads();
    }
    int pos = csum[tid] - c;
    if (tid == 255) cnt[e] = csum[255];
    for (int i = 0; i < per; i++) {
        const int t = tid * per + i;
        const int4   id4 = ((const int4*)tidx)[t];
        const float4 w4  = ((const float4*)tw)[t];
        float w = 0.f; int hit = 0;
        if      (id4.x == e) { w = w4.x; hit = 1; }
        else if (id4.y == e) { w = w4.y; hit = 1; }
        else if (id4.z == e) { w = w4.z; hit = 1; }
        else if (id4.w == e) { w = w4.w; hit = 1; }
        if (hit) { tok[(long)e * N + pos] = t; wl[(long)e * N + pos] = w; pos++; }
    }
}

// ---------------- gather rows: xg[z][pos] = xb[tok[z][pos]] -----------------
// 4 rows per block; 64 lanes x 16B = 1KB/iter, 4 iters per 4KB row.
__global__ __launch_bounds__(256) void gather_rows(const bf16* __restrict__ xb,
        const int* __restrict__ tok, long tokz, const int* __restrict__ cnt,
        bf16* __restrict__ xg, long xgz, int C) {
    const int z = blockIdx.z;
    const int pos = blockIdx.x * 4 + (threadIdx.x >> 6);
    if (pos >= cnt[z]) return;
    const int lane = threadIdx.x & 63;
    const ulonglong2* s = (const ulonglong2*)(xb + (long)tok[z * tokz + pos] * C);
    ulonglong2* d = (ulonglong2*)(xg + z * xgz + (long)pos * C);
    #pragma unroll
    for (int i = 0; i < 4; i++) d[lane + i * 64] = s[lane + i * 64];
}

// -------- fused gate+up GEMM (z-batched): H = silu(xg)*xu*sc ---------------
// Tile 128x64, BK=64, 4 waves (2x2). tok!=null -> in-GEMM gather (fallback);
// az!=0 -> A advances per z (pre-gathered mode).
__global__ __launch_bounds__(256) void dual_gemm(const bf16* __restrict__ A,
        long az, const int* __restrict__ tok, long tokz,
        const int* __restrict__ cnt, int Mfix,
        const bf16* __restrict__ BG0, const bf16* __restrict__ BU0, long bz,
        bf16* __restrict__ H0, long hld, long hz,
        const float* __restrict__ sc0, long scz, int K) {
    __shared__ __align__(128) char Al[16384];
    __shared__ __align__(128) char Gl[8192];
    __shared__ __align__(128) char Ul[8192];
    const int z = blockIdx.z;
    const int Me = cnt ? cnt[z] : Mfix;
    const long m0 = (long)blockIdx.x * 128;
    if (m0 >= Me) return;
    const bf16* Az = A + (long)z * az;
    const int* ridx = tok ? tok + (long)z * tokz : nullptr;
    const bf16* BG = BG0 + (long)z * bz;
    const bf16* BU = BU0 + (long)z * bz;
    bf16* H = H0 + (long)z * hz;
    const float* sc = sc0 + (long)z * scz;
    const int tid = threadIdx.x, lane = tid & 63, wid = tid >> 6;
    const long n0 = (long)blockIdx.y * 64;
    const int wm = (wid >> 1) * 64, wn = (wid & 1) * 32;
    const int l15 = lane & 15, lhi = lane >> 4;
    const int swz = ((lane & 7) ^ (lane >> 3)) << 4;
    long roffA[4];
    #pragma unroll
    for (int i = 0; i < 4; i++) {
        const int rit = ((i * 4096 + wid * 1024) >> 7) + (lane >> 3);
        int g = (int)m0 + rit;
        if (ridx) g = ridx[g < Me ? g : Me - 1];
        roffA[i] = (long)g * (K * 2);
    }
    f32x4 ag[4][2] = {}; f32x4 au[4][2] = {};
    for (int kt = 0; kt < K; kt += 64) {
        stage_idx<128>((const char*)Az, roffA, kt * 2, Al, tid, swz);
        stage<64>(BG + n0 * K + kt, (long)K, Gl, tid);
        stage<64>(BU + n0 * K + kt, (long)K, Ul, tid);
        __syncthreads();
        #pragma unroll
        for (int ks = 0; ks < 2; ks++) {
            const int kb = ks * 64 + lhi * 16;
            i32x4 af[4], bg[2], bu[2];
            #pragma unroll
            for (int mi = 0; mi < 4; mi++) af[mi] = ldsfrag(Al, wm + mi * 16 + l15, kb);
            #pragma unroll
            for (int ni = 0; ni < 2; ni++) {
                bg[ni] = ldsfrag(Gl, wn + ni * 16 + l15, kb);
                bu[ni] = ldsfrag(Ul, wn + ni * 16 + l15, kb);
            }
            #pragma unroll
            for (int mi = 0; mi < 4; mi++) {
                #pragma unroll
                for (int ni = 0; ni < 2; ni++) {
                    mfma16(ag[mi][ni], af[mi], bg[ni]);
                    mfma16(au[mi][ni], af[mi], bu[ni]);
                }
            }
        }
        __syncthreads();
    }
    asm volatile("s_nop 7\n\ts_nop 7\n\ts_nop 7");
    #pragma unroll
    for (int mi = 0; mi < 4; mi++) {
        #pragma unroll
        for (int r = 0; r < 4; r++) {
            const int pos = (int)m0 + wm + mi * 16 + lhi * 4 + r;
            if (pos < Me) {
                const float s = sc[pos];
                #pragma unroll
                for (int ni = 0; ni < 2; ni++) {
                    const float gv = ag[mi][ni][r], uv = au[mi][ni][r];
                    const float h = (gv / (1.f + expf(-gv))) * uv * s;
                    H[(long)pos * hld + n0 + wn + ni * 16 + l15] = __float2bfloat16(h);
                }
            }
        }
    }
}

// ------ down GEMM: C[row(pos)] (+)= A[pos,:K] * BT^T, scatter rows ----------
__global__ __launch_bounds__(256) void gemm_down(const bf16* __restrict__ A,
        const bf16* __restrict__ BT, float* __restrict__ C,
        const int* __restrict__ ridx, const int* __restrict__ cntp, int Mfix,
        int K, long ldc, int beta) {
    __shared__ __align__(128) char Al[16384];
    __shared__ __align__(128) char Bl[16384];
    const int Me = cntp ? *cntp : Mfix;
    const long m0 = (long)blockIdx.y * 128;
    if (m0 >= Me) return;
    const int tid = threadIdx.x, lane = tid & 63, wid = tid >> 6;
    const long n0 = (long)blockIdx.x * 128;
    const int wm = (wid >> 1) * 64, wn = (wid & 1) * 64;
    const int l15 = lane & 15, lhi = lane >> 4;
    f32x4 acc[4][4] = {};
    for (int kt = 0; kt < K; kt += 64) {
        stage<128>(A  + m0 * K + kt, (long)K, Al, tid);
        stage<128>(BT + n0 * K + kt, (long)K, Bl, tid);
        __syncthreads();
        #pragma unroll
        for (int ks = 0; ks < 2; ks++) {
            const int kb = ks * 64 + lhi * 16;
            i32x4 af[4], bfr[4];
            #pragma unroll
            for (int mi = 0; mi < 4; mi++) af[mi]  = ldsfrag(Al, wm + mi * 16 + l15, kb);
            #pragma unroll
            for (int ni = 0; ni < 4; ni++) bfr[ni] = ldsfrag(Bl, wn + ni * 16 + l15, kb);
            #pragma unroll
            for (int mi = 0; mi < 4; mi++) {
                #pragma unroll
                for (int ni = 0; ni < 4; ni++) mfma16(acc[mi][ni], af[mi], bfr[ni]);
            }
        }
        __syncthreads();
    }
    asm volatile("s_nop 7\n\ts_nop 7\n\ts_nop 7");
    #pragma unroll
    for (int mi = 0; mi < 4; mi++) {
        #pragma unroll
        for (int r = 0; r < 4; r++) {
            const int pos = (int)m0 + wm + mi * 16 + lhi * 4 + r;
            if (pos < Me) {
                const long orow = ridx ? (long)ridx[pos] : (long)pos;
                #pragma unroll
                for (int ni = 0; ni < 4; ni++) {
                    const long ci = orow * ldc + n0 + wn + ni * 16 + l15;
                    float v = acc[mi][ni][r];
                    if (beta) v += C[ci];
                    C[ci] = v;
                }
            }
        }
    }
}

extern "C" void kernel_launch(void* const* d_in, const int* in_sizes, int n_in,
                              void* d_out, int out_size, void* d_ws, size_t ws_size,
                              hipStream_t stream) {
    const int N = 8192, Cdim = 2048, E = 8, I = 1408, SI = 5632;

    const float* x    = (const float*)d_in[0];
    const float* gw   = (const float*)d_in[1];
    const float* egw  = (const float*)d_in[2];
    const float* euw  = (const float*)d_in[3];
    const float* edw  = (const float*)d_in[4];
    const float* sgw  = (const float*)d_in[5];
    const float* suw  = (const float*)d_in[6];
    const float* sdw  = (const float*)d_in[7];
    const float* segw = (const float*)d_in[8];
    float* out = (float*)d_out;

    char* ws = (char*)d_ws;
    size_t off = 0;
    auto alloc = [&](size_t bytes) { char* p = ws + off; off += (bytes + 255) & ~(size_t)255; return p; };

    bf16*  xb   = (bf16*) alloc((size_t)N * Cdim * 2);   // 33.6 MB
    int*   tidx = (int*)  alloc((size_t)N * 4 * 4);
    float* tw   = (float*)alloc((size_t)N * 4 * 4);
    float* sg   = (float*)alloc((size_t)N * 4);
    int*   tok  = (int*)  alloc((size_t)E * N * 4);
    float* wl   = (float*)alloc((size_t)E * N * 4);
    int*   cnt  = (int*)  alloc(256);

    const size_t WSLOT = (size_t)SI * Cdim * 2;          // 23.1 MB (4 experts)
    bf16* Wa = (bf16*)alloc(WSLOT);
    bf16* Wb = (bf16*)alloc(WSLOT);
    bf16* Wc = (bf16*)alloc(WSLOT);
    bf16* Hc = (bf16*)alloc((size_t)N * SI * 2);         // 92.3 MB
    if (off > ws_size) return;                           // base 196 MB (proven)

    // Adaptive gather batch: GB in {4,2,1,0}; xg = GB * N rows of C bf16.
    const size_t ROWB = (size_t)N * Cdim * 2;            // 33.6 MB per z-slice
    int GB = 0;
    if      (off + 4 * ROWB <= ws_size) GB = 4;
    else if (off + 2 * ROWB <= ws_size) GB = 2;
    else if (off + 1 * ROWB <= ws_size) GB = 1;
    bf16* xg = (GB > 0) ? (bf16*)alloc((size_t)GB * ROWB) : nullptr;

    cvtx<<<4096, 256, 0, stream>>>(x, xb, (long)N * Cdim / 4);
    router<<<N / 4, 256, 0, stream>>>(x, gw, segw, tidx, tw, sg, Cdim);
    build_lists<<<E, 256, 0, stream>>>(tidx, tw, tok, wl, cnt, N);

    // ---------------- shared expert (beta=0 covers d_out) -------------------
    tcvt<<<dim3(SI / 64, Cdim / 64, 1), 256, 0, stream>>>(sgw, Wa, SI, (long)Cdim, 0, 0);
    tcvt<<<dim3(SI / 64, Cdim / 64, 1), 256, 0, stream>>>(suw, Wb, SI, (long)Cdim, 0, 0);
    tcvt<<<dim3(Cdim / 64, SI / 64, 1), 256, 0, stream>>>(sdw, Wc, Cdim, (long)SI, 0, 0);
    dual_gemm<<<dim3(N / 128, SI / 64, 1), 256, 0, stream>>>(xb, 0,
            nullptr, 0, nullptr, N, Wa, Wb, 0, Hc, (long)SI, 0, sg, 0, Cdim);
    gemm_down<<<dim3(Cdim / 128, N / 128), 256, 0, stream>>>(Hc, Wc, out,
            nullptr, nullptr, N, SI, (long)Cdim, 0);

    // ---------------- routed experts: 2 weight-batches of 4 -----------------
    for (int b = 0; b < 2; b++) {
        const int e0 = b * 4;
        tcvt<<<dim3(I / 64, Cdim / 64, 4), 256, 0, stream>>>(
                egw + (long)e0 * Cdim * I, Wa, I, (long)Cdim,
                (long)Cdim * I, (long)I * Cdim);
        tcvt<<<dim3(I / 64, Cdim / 64, 4), 256, 0, stream>>>(
                euw + (long)e0 * Cdim * I, Wb, I, (long)Cdim,
                (long)Cdim * I, (long)I * Cdim);
        tcvt<<<dim3(Cdim / 64, I / 64, 4), 256, 0, stream>>>(
                edw + (long)e0 * I * Cdim, Wc, Cdim, (long)I,
                (long)I * Cdim, (long)Cdim * I);

        if (GB > 0) {
            for (int s = 0; s < 4; s += GB) {
                gather_rows<<<dim3(N / 4, 1, GB), 256, 0, stream>>>(xb,
                        tok + (long)(e0 + s) * N, (long)N, cnt + e0 + s,
                        xg, (long)N * Cdim, Cdim);
                dual_gemm<<<dim3(N / 128, I / 64, GB), 256, 0, stream>>>(
                        xg, (long)N * Cdim, nullptr, 0, cnt + e0 + s, 0,
                        Wa + (long)s * I * Cdim, Wb + (long)s * I * Cdim,
                        (long)I * Cdim,
                        Hc + (long)s * N * I, (long)I, (long)N * I,
                        wl + (long)(e0 + s) * N, (long)N, Cdim);
            }
        } else {
            dual_gemm<<<dim3(N / 128, I / 64, 4), 256, 0, stream>>>(xb, 0,
                    tok + (long)e0 * N, (long)N, cnt + e0, 0,
                    Wa, Wb, (long)I * Cdim,
                    Hc, (long)I, (long)N * I,
                    wl + (long)e0 * N, (long)N, Cdim);
        }

        for (int z = 0; z < 4; z++) {
            gemm_down<<<dim3(Cdim / 128, N / 128), 256, 0, stream>>>(
                    Hc + (long)z * N * I, Wc + (long)z * Cdim * I, out,
                    tok + (long)(e0 + z) * N, cnt + e0 + z, 0,
                    I, (long)Cdim, 1);
        }
    }
}